// Round 5
// baseline (907.900 us; speedup 1.0000x reference)
//
#include <hip/hip_runtime.h>
#include <cstdint>
#include <cstddef>

#define H_DIM 1024
#define F_DIM 4096
#define N_EXP 8
#define N_TOK 8192
#define NK_ASSIGN (N_TOK * 2)
#define MAX_MB 24  // max M-blocks/expert at BM=128 = 3072 tokens; actual ~2048±50 (>20 sigma)
#define NMB 32     // meta blocks: 8192 tokens / 256 threads

typedef unsigned short u16;
typedef __attribute__((ext_vector_type(8))) short bf16x8;
typedef __attribute__((ext_vector_type(4))) float f32x4;

// RNE float -> bf16 bits (finite inputs only)
__device__ __forceinline__ u16 f2bf(float f) {
  unsigned int u = __float_as_uint(f);
  u += 0x7fffu + ((u >> 16) & 1u);
  return (u16)(u >> 16);
}

// async global->LDS, 16B per lane. lds ptr MUST be wave-uniform (HW adds lane*16).
__device__ __forceinline__ void load16(const u16* g, u16* l) {
  __builtin_amdgcn_global_load_lds(
      (const __attribute__((address_space(1))) void*)g,
      (__attribute__((address_space(3))) void*)l, 16, 0, 0);
}

// ---------------- router: fp32 logits, top-2, gates; also emits xb = bf16(x) --
// NO global atomics (counts come from hist_kernel).
__global__ __launch_bounds__(256) void router_kernel(
    const float* __restrict__ x, const float* __restrict__ rw,
    const float* __restrict__ rb, int* __restrict__ topk_idx,
    float* __restrict__ topk_w, u16* __restrict__ xb) {
  const int lane = threadIdx.x & 63;
  const int wid = threadIdx.x >> 6;
  const int t = blockIdx.x * 4 + wid;  // one wave per token
  const float4* xr = (const float4*)(x + (size_t)t * H_DIM);
  u16* xo = xb + (size_t)t * H_DIM;
  float acc[N_EXP];
#pragma unroll
  for (int e = 0; e < N_EXP; ++e) acc[e] = 0.f;
#pragma unroll
  for (int j = 0; j < 4; ++j) {
    float4 xv = xr[j * 64 + lane];
    // side product: bf16 copy of x (replaces the old gather kernel)
    ushort4 u;
    u.x = f2bf(xv.x); u.y = f2bf(xv.y); u.z = f2bf(xv.z); u.w = f2bf(xv.w);
    *(ushort4*)(xo + (size_t)(j * 64 + lane) * 4) = u;
#pragma unroll
    for (int e = 0; e < N_EXP; ++e) {
      float4 wv = ((const float4*)(rw + e * H_DIM))[j * 64 + lane];
      acc[e] += xv.x * wv.x + xv.y * wv.y + xv.z * wv.z + xv.w * wv.w;
    }
  }
#pragma unroll
  for (int off = 32; off > 0; off >>= 1) {
#pragma unroll
    for (int e = 0; e < N_EXP; ++e) acc[e] += __shfl_xor(acc[e], off);
  }
  if (lane == 0) {
    float lg[N_EXP];
#pragma unroll
    for (int e = 0; e < N_EXP; ++e) lg[e] = acc[e] + rb[e];
    int i0 = 0;
    float b0 = lg[0];
#pragma unroll
    for (int e = 1; e < N_EXP; ++e)
      if (lg[e] > b0) { b0 = lg[e]; i0 = e; }  // strict > : lowest index wins ties
    int i1 = -1;
    float b1 = -3.4e38f;
#pragma unroll
    for (int e = 0; e < N_EXP; ++e)
      if (e != i0 && lg[e] > b1) { b1 = lg[e]; i1 = e; }
    float w0 = 1.f / (1.f + __expf(b1 - b0));  // p0/(p0+p1)
    topk_idx[2 * t] = i0;
    topk_idx[2 * t + 1] = i1;
    topk_w[2 * t] = w0;
    topk_w[2 * t + 1] = 1.f - w0;
  }
}

// ---------------- per-block expert histogram (LDS atomics only) --------------
__global__ __launch_bounds__(256) void hist_kernel(
    const int* __restrict__ topk_idx, int* __restrict__ hist_g) {
  __shared__ int hh[N_EXP];
  const int tid = threadIdx.x;
  if (tid < N_EXP) hh[tid] = 0;
  __syncthreads();
  const int t = blockIdx.x * 256 + tid;
  const int e0 = topk_idx[2 * t], e1 = topk_idx[2 * t + 1];
  atomicAdd(&hh[e0], 1);
  atomicAdd(&hh[e1], 1);
  __syncthreads();
  if (tid < N_EXP) hist_g[blockIdx.x * N_EXP + tid] = hh[tid];
}

// ---------------- scatter (scan folded in): LDS cursors, no global atomics ---
// Each block recomputes the 256-int prefix locally (trivial); block 0 also
// publishes offsets[9] for the GEMMs.
__global__ __launch_bounds__(256) void scatter_kernel(
    const int* __restrict__ topk_idx, const float* __restrict__ topk_w,
    const int* __restrict__ hist_g, int* __restrict__ offsets,
    int* __restrict__ assign_token, float* __restrict__ assign_gate,
    int* __restrict__ slot_of) {
  __shared__ int sh[NMB * N_EXP];
  __shared__ int pb[N_EXP];
  __shared__ int cur[N_EXP];
  const int tid = threadIdx.x;
  sh[tid] = hist_g[tid];  // 256 == NMB*N_EXP
  if (tid < N_EXP) cur[tid] = 0;
  __syncthreads();
  if (tid == 0) {
    int tot[N_EXP];
    for (int e = 0; e < N_EXP; ++e) tot[e] = 0;
    for (int b = 0; b < NMB; ++b)
      for (int e = 0; e < N_EXP; ++e) tot[e] += sh[b * N_EXP + e];
    int run = 0;
    for (int e = 0; e < N_EXP; ++e) {
      if (blockIdx.x == 0) offsets[e] = run;
      int r = run;
      for (int b = 0; b < (int)blockIdx.x; ++b) r += sh[b * N_EXP + e];
      pb[e] = r;
      run += tot[e];
    }
    if (blockIdx.x == 0) offsets[N_EXP] = run;  // == 16384
  }
  __syncthreads();
  const int t = blockIdx.x * 256 + tid;
#pragma unroll
  for (int k = 0; k < 2; ++k) {
    int e = topk_idx[2 * t + k];
    int local = atomicAdd(&cur[e], 1);
    int pos = pb[e] + local;
    assign_token[pos] = t;
    assign_gate[pos] = topk_w[2 * t + k];
    slot_of[2 * t + k] = pos;  // inverse map for combine
  }
}

// ---------------- fp32 [E][R][C] -> bf16 [E][C][R] (transpose + convert) -----
__global__ __launch_bounds__(256) void transpose_cvt(
    const float* __restrict__ in, u16* __restrict__ out, int R, int C) {
  __shared__ u16 lds[64 * 66];
  const int e = blockIdx.z;
  const float* ip = in + (size_t)e * R * C;
  u16* op = out + (size_t)e * R * C;
  const int c0 = blockIdx.x * 64, r0 = blockIdx.y * 64;
  const int tid = threadIdx.x;
  const int tx = tid & 15, ty = tid >> 4;
#pragma unroll
  for (int i = 0; i < 4; ++i) {
    const int r = ty + i * 16;
    float4 v = *(const float4*)(ip + (size_t)(r0 + r) * C + c0 + tx * 4);
    ushort2 u01, u23;
    u01.x = f2bf(v.x); u01.y = f2bf(v.y);
    u23.x = f2bf(v.z); u23.y = f2bf(v.w);
    *(ushort2*)&lds[r * 66 + tx * 4] = u01;
    *(ushort2*)&lds[r * 66 + tx * 4 + 2] = u23;
  }
  __syncthreads();
  const int lane = tid & 63, wid = tid >> 6;
  const int r8 = lane & 7;
#pragma unroll
  for (int s = 0; s < 2; ++s) {
    const int c = s * 32 + wid * 8 + (lane >> 3);
    union { u16 u[8]; uint4 q; } pk;
#pragma unroll
    for (int k = 0; k < 8; ++k) pk.u[k] = lds[(r8 * 8 + k) * 66 + c];
    *(uint4*)(op + (size_t)(c0 + c) * R + r0 + r8 * 8) = pk.q;
  }
}

// ---------------- grouped GEMM: C[M][N] = A[M][K] * B[N][K]^T ---------------
// 128x128 tile, BK=64 (half the barrier drains of BK=32), 4 waves, 32 KB LDS,
// ~3 blocks/CU (implicit m114 wave-level overlap hides the vmcnt drain).
// LDS XOR swizzle (both-sides, rule #21): LDS[r][sl] holds G[r][sl^(r&7)]
// via pre-swizzled global source col; reads XOR the same -> benign 8-way
// (= b128 bandwidth floor). Without it BK=64's 128B rows are 16-way (2x floor).
// XCD-aware remap (T1): expert e -> XCD e, mb fastest -> B panels L2-local
// (r4 measured FETCH 614->146 MB).
// FIRST:  A=xb(indirect via atok), B=w1b, epilogue = tanh-gelu -> bf16 -> h
// !FIRST: A=h (direct),            B=w2b, epilogue = *gate, fp32 -> y_slot
template <int LDA, int LDB, int LDC, int KITERS, int NXB, bool FIRST>
__global__ __launch_bounds__(256) void moe_gemm(
    const u16* __restrict__ Abase, const u16* __restrict__ Bbase,
    u16* __restrict__ hout, float* __restrict__ yout,
    const int* __restrict__ offsets, const float* __restrict__ assign_gate,
    const int* __restrict__ atok) {
  __shared__ __align__(16) u16 As[128 * 64];  // 16 KB
  __shared__ __align__(16) u16 Bs[128 * 64];  // 16 KB
  // ---- XCD-aware remap: xcd = flat%8 owns expert xcd; mb varies fastest ----
  const int flat = blockIdx.x + NXB * (blockIdx.y + MAX_MB * blockIdx.z);
  const int e = flat & 7;
  const int s = flat >> 3;           // 0 .. NXB*MAX_MB-1
  const int mb = s % MAX_MB;
  const int n0b = s / MAX_MB;        // 0 .. NXB-1
  const int row0 = offsets[e];
  const int cnt = offsets[e + 1] - row0;
  const int mbase = mb * 128;
  if (mbase >= cnt) return;  // block-uniform early exit
  const int mrem = cnt - mbase;
  const int n0 = n0b * 128;
  const int tid = threadIdx.x;
  const int lane = tid & 63;
  const int wid = tid >> 6;
  const int wm = wid & 1, wn = wid >> 1;
  const u16* B = Bbase + (size_t)e * ((size_t)H_DIM * F_DIM);
  const int row16 = lane & 15, quad = lane >> 4;
  // staging: chunk = 8 rows x 128B; wave covers 4 A-chunks + 4 B-chunks/iter
  const int sr = lane >> 3;                 // row within 8-row chunk (== r&7)
  const int scol = ((lane & 7) ^ sr) * 8;   // pre-swizzled source col (elems)

  // hoist per-thread A/B row pointers out of the K-loop (FIRST folds the
  // assign_token indirection here, once).
  const u16* Arow[4];
  const u16* Brow[4];
#pragma unroll
  for (int i = 0; i < 4; ++i) {
    const int c = wid * 4 + i;           // chunk 0..15
    const int r = c * 8 + sr;
    const int ra = min(r, mrem - 1);     // clamp: stay inside valid A rows
    if (FIRST) {
      const int tok = atok[row0 + mbase + ra];
      Arow[i] = Abase + (size_t)tok * LDA + scol;
    } else {
      Arow[i] = Abase + (size_t)(row0 + mbase + ra) * LDA + scol;
    }
    Brow[i] = B + (size_t)(n0 + r) * LDB + scol;
  }

  f32x4 acc[4][4];
#pragma unroll
  for (int i = 0; i < 4; ++i)
#pragma unroll
    for (int j = 0; j < 4; ++j)
#pragma unroll
      for (int r = 0; r < 4; ++r) acc[i][j][r] = 0.f;

  for (int kt = 0; kt < KITERS; ++kt) {
    const int k0 = kt * 64;
#pragma unroll
    for (int i = 0; i < 4; ++i) {
      const int c = wid * 4 + i;
      load16(Arow[i] + k0, &As[c * 512]);
      load16(Brow[i] + k0, &Bs[c * 512]);
    }
    __syncthreads();  // drains vmcnt -> LDS tiles complete
#pragma unroll
    for (int ks = 0; ks < 2; ++ks) {
      bf16x8 av[4], bv[4];
#pragma unroll
      for (int mi = 0; mi < 4; ++mi) {
        const int r = wm * 64 + mi * 16 + row16;
        av[mi] = *(const bf16x8*)&As[r * 64 + ((ks * 4 + quad) ^ (r & 7)) * 8];
      }
#pragma unroll
      for (int ni = 0; ni < 4; ++ni) {
        const int r = wn * 64 + ni * 16 + row16;
        bv[ni] = *(const bf16x8*)&Bs[r * 64 + ((ks * 4 + quad) ^ (r & 7)) * 8];
      }
#pragma unroll
      for (int mi = 0; mi < 4; ++mi)
#pragma unroll
        for (int ni = 0; ni < 4; ++ni)
          acc[mi][ni] =
              __builtin_amdgcn_mfma_f32_16x16x32_bf16(av[mi], bv[ni], acc[mi][ni], 0, 0, 0);
    }
    __syncthreads();
  }

  // C/D layout: col = lane&15 (n), row = quad*4 + reg (m)
  if (FIRST) {
    u16* Cp = hout + (size_t)(row0 + mbase) * LDC + n0;
#pragma unroll
    for (int mi = 0; mi < 4; ++mi) {
#pragma unroll
      for (int r = 0; r < 4; ++r) {
        const int lm = wm * 64 + mi * 16 + quad * 4 + r;
        if (lm < mrem) {
#pragma unroll
          for (int ni = 0; ni < 4; ++ni) {
            float v = acc[mi][ni][r];
            // tanh-approx gelu via sigmoid: v * sigmoid(2*sqrt(2/pi)*(v+0.044715v^3))
            float t = v * (0.7978845608028654f + 0.0356774081363f * v * v);
            v = v / (1.f + __expf(-2.f * t));
            Cp[(size_t)lm * LDC + (wn * 64 + ni * 16 + row16)] = f2bf(v);
          }
        }
      }
    }
  } else {
#pragma unroll
    for (int mi = 0; mi < 4; ++mi) {
#pragma unroll
      for (int r = 0; r < 4; ++r) {
        const int lm = wm * 64 + mi * 16 + quad * 4 + r;
        if (lm < mrem) {
          const int slot = row0 + mbase + lm;
          const float g = assign_gate[slot];
          float* orow = yout + (size_t)slot * LDC + n0;
#pragma unroll
          for (int ni = 0; ni < 4; ++ni)
            orow[wn * 64 + ni * 16 + row16] = acc[mi][ni][r] * g;
        }
      }
    }
  }
}

// ---------------- combine: out[t] = y_slot[s0] + y_slot[s1] ------------------
__global__ __launch_bounds__(256) void combine_kernel(
    const float* __restrict__ ys, const int* __restrict__ slot_of,
    float* __restrict__ out) {
  const int t = blockIdx.x;
  const int s0 = slot_of[2 * t], s1 = slot_of[2 * t + 1];
  const int i = threadIdx.x;
  float4 a = ((const float4*)(ys + (size_t)s0 * H_DIM))[i];
  float4 b = ((const float4*)(ys + (size_t)s1 * H_DIM))[i];
  float4 o;
  o.x = a.x + b.x; o.y = a.y + b.y; o.z = a.z + b.z; o.w = a.w + b.w;
  ((float4*)(out + (size_t)t * H_DIM))[i] = o;
}

extern "C" void kernel_launch(void* const* d_in, const int* in_sizes, int n_in,
                              void* d_out, int out_size, void* d_ws, size_t ws_size,
                              hipStream_t stream) {
  const float* x = (const float*)d_in[0];
  const float* rw = (const float*)d_in[1];
  const float* rb = (const float*)d_in[2];
  const float* w1 = (const float*)d_in[3];
  const float* w2 = (const float*)d_in[4];
  float* out = (float*)d_out;

  char* ws = (char*)d_ws;
  // workspace layout (~302.4 MB total)
  u16* w1b = (u16*)(ws);                        // [E][F][H] bf16   67,108,864 B
  float* y_slot = (float*)(ws);                 // [16384][H] fp32 -- ALIASES w1b
                                                // (w1b dead after GEMM1; GEMM2 writes here)
  u16* w2b = (u16*)(ws + 67108864);             // [E][H][F] bf16   67,108,864 B
  u16* xb = (u16*)(ws + 134217728);             // [8192][H] bf16   16,777,216 B
  u16* h = (u16*)(ws + 167772160);              // [16384][F] bf16 134,217,728 B
  // hist borrows the head of the h region (dead before GEMM1 writes h)
  int* hist_g = (int*)(ws + 167772160);         // [32][8] ints (1 KB)
  char* meta = ws + 301989888;
  int* offsets = (int*)(meta + 64);             // 9 ints
  int* topk_idx = (int*)(meta + 128);           // 16384 ints
  float* topk_w = (float*)(meta + 128 + 65536);
  int* assign_token = (int*)(meta + 128 + 131072);
  float* assign_gate = (float*)(meta + 128 + 196608);
  int* slot_of = (int*)(meta + 128 + 262144);

  router_kernel<<<N_TOK / 4, 256, 0, stream>>>(x, rw, rb, topk_idx, topk_w, xb);
  hist_kernel<<<NMB, 256, 0, stream>>>(topk_idx, hist_g);
  scatter_kernel<<<NMB, 256, 0, stream>>>(topk_idx, topk_w, hist_g, offsets,
                                          assign_token, assign_gate, slot_of);
  // w1 [E][1024][4096] -> w1b [E][4096][1024]
  transpose_cvt<<<dim3(F_DIM / 64, H_DIM / 64, N_EXP), 256, 0, stream>>>(w1, w1b, H_DIM, F_DIM);
  // w2 [E][4096][1024] -> w2b [E][1024][4096]
  transpose_cvt<<<dim3(H_DIM / 64, F_DIM / 64, N_EXP), 256, 0, stream>>>(w2, w2b, F_DIM, H_DIM);

  // GEMM1: [cnt_e][1024] (indirect rows of xb) @ [4096][1024]^T -> gelu -> h
  moe_gemm<H_DIM, H_DIM, F_DIM, H_DIM / 64, F_DIM / 128, true>
      <<<dim3(F_DIM / 128, MAX_MB, N_EXP), 256, 0, stream>>>(
          xb, w1b, h, nullptr, offsets, assign_gate, assign_token);
  // GEMM2: [cnt_e][4096] @ [1024][4096]^T -> *gate -> y_slot [16384][1024]
  moe_gemm<F_DIM, F_DIM, H_DIM, F_DIM / 64, H_DIM / 128, false>
      <<<dim3(H_DIM / 128, MAX_MB, N_EXP), 256, 0, stream>>>(
          h, w2b, nullptr, y_slot, offsets, assign_gate, nullptr);
  // out[t] = y_slot[slot0(t)] + y_slot[slot1(t)]
  combine_kernel<<<N_TOK, 256, 0, stream>>>(y_slot, slot_of, out);

  (void)in_sizes; (void)n_in; (void)ws_size;
}

// Round 6
// 807.633 us; speedup vs baseline: 1.1241x; 1.1241x over previous
//
#include <hip/hip_runtime.h>
#include <cstdint>
#include <cstddef>

#define H_DIM 1024
#define F_DIM 4096
#define N_EXP 8
#define N_TOK 8192
#define NK_ASSIGN (N_TOK * 2)
#define MAX_MB 24  // max M-blocks/expert at BM=128 = 3072 tokens; actual ~2048±50 (>20 sigma)
#define NMB 32     // meta blocks: 8192 tokens / 256 threads

typedef unsigned short u16;
typedef __attribute__((ext_vector_type(8))) short bf16x8;
typedef __attribute__((ext_vector_type(4))) float f32x4;

// RNE float -> bf16 bits (finite inputs only)
__device__ __forceinline__ u16 f2bf(float f) {
  unsigned int u = __float_as_uint(f);
  u += 0x7fffu + ((u >> 16) & 1u);
  return (u16)(u >> 16);
}

// async global->LDS, 16B per lane. lds ptr MUST be wave-uniform (HW adds lane*16).
__device__ __forceinline__ void load16(const u16* g, u16* l) {
  __builtin_amdgcn_global_load_lds(
      (const __attribute__((address_space(1))) void*)g,
      (__attribute__((address_space(3))) void*)l, 16, 0, 0);
}

// ---------------- router: fp32 logits, top-2, gates; also emits xb = bf16(x) --
// NO global atomics (counts come from hist_kernel).
__global__ __launch_bounds__(256) void router_kernel(
    const float* __restrict__ x, const float* __restrict__ rw,
    const float* __restrict__ rb, int* __restrict__ topk_idx,
    float* __restrict__ topk_w, u16* __restrict__ xb) {
  const int lane = threadIdx.x & 63;
  const int wid = threadIdx.x >> 6;
  const int t = blockIdx.x * 4 + wid;  // one wave per token
  const float4* xr = (const float4*)(x + (size_t)t * H_DIM);
  u16* xo = xb + (size_t)t * H_DIM;
  float acc[N_EXP];
#pragma unroll
  for (int e = 0; e < N_EXP; ++e) acc[e] = 0.f;
#pragma unroll
  for (int j = 0; j < 4; ++j) {
    float4 xv = xr[j * 64 + lane];
    // side product: bf16 copy of x (replaces the old gather kernel)
    ushort4 u;
    u.x = f2bf(xv.x); u.y = f2bf(xv.y); u.z = f2bf(xv.z); u.w = f2bf(xv.w);
    *(ushort4*)(xo + (size_t)(j * 64 + lane) * 4) = u;
#pragma unroll
    for (int e = 0; e < N_EXP; ++e) {
      float4 wv = ((const float4*)(rw + e * H_DIM))[j * 64 + lane];
      acc[e] += xv.x * wv.x + xv.y * wv.y + xv.z * wv.z + xv.w * wv.w;
    }
  }
#pragma unroll
  for (int off = 32; off > 0; off >>= 1) {
#pragma unroll
    for (int e = 0; e < N_EXP; ++e) acc[e] += __shfl_xor(acc[e], off);
  }
  if (lane == 0) {
    float lg[N_EXP];
#pragma unroll
    for (int e = 0; e < N_EXP; ++e) lg[e] = acc[e] + rb[e];
    int i0 = 0;
    float b0 = lg[0];
#pragma unroll
    for (int e = 1; e < N_EXP; ++e)
      if (lg[e] > b0) { b0 = lg[e]; i0 = e; }  // strict > : lowest index wins ties
    int i1 = -1;
    float b1 = -3.4e38f;
#pragma unroll
    for (int e = 0; e < N_EXP; ++e)
      if (e != i0 && lg[e] > b1) { b1 = lg[e]; i1 = e; }
    float w0 = 1.f / (1.f + __expf(b1 - b0));  // p0/(p0+p1)
    topk_idx[2 * t] = i0;
    topk_idx[2 * t + 1] = i1;
    topk_w[2 * t] = w0;
    topk_w[2 * t + 1] = 1.f - w0;
  }
}

// ---------------- per-block expert histogram (LDS atomics only) --------------
__global__ __launch_bounds__(256) void hist_kernel(
    const int* __restrict__ topk_idx, int* __restrict__ hist_g) {
  __shared__ int hh[N_EXP];
  const int tid = threadIdx.x;
  if (tid < N_EXP) hh[tid] = 0;
  __syncthreads();
  const int t = blockIdx.x * 256 + tid;
  const int e0 = topk_idx[2 * t], e1 = topk_idx[2 * t + 1];
  atomicAdd(&hh[e0], 1);
  atomicAdd(&hh[e1], 1);
  __syncthreads();
  if (tid < N_EXP) hist_g[blockIdx.x * N_EXP + tid] = hh[tid];
}

// ---------------- scatter (scan folded in): LDS cursors, no global atomics ---
// Each block recomputes the 256-int prefix locally (trivial); block 0 also
// publishes offsets[9] for the GEMMs.
__global__ __launch_bounds__(256) void scatter_kernel(
    const int* __restrict__ topk_idx, const float* __restrict__ topk_w,
    const int* __restrict__ hist_g, int* __restrict__ offsets,
    int* __restrict__ assign_token, float* __restrict__ assign_gate,
    int* __restrict__ slot_of) {
  __shared__ int sh[NMB * N_EXP];
  __shared__ int pb[N_EXP];
  __shared__ int cur[N_EXP];
  const int tid = threadIdx.x;
  sh[tid] = hist_g[tid];  // 256 == NMB*N_EXP
  if (tid < N_EXP) cur[tid] = 0;
  __syncthreads();
  if (tid == 0) {
    int tot[N_EXP];
    for (int e = 0; e < N_EXP; ++e) tot[e] = 0;
    for (int b = 0; b < NMB; ++b)
      for (int e = 0; e < N_EXP; ++e) tot[e] += sh[b * N_EXP + e];
    int run = 0;
    for (int e = 0; e < N_EXP; ++e) {
      if (blockIdx.x == 0) offsets[e] = run;
      int r = run;
      for (int b = 0; b < (int)blockIdx.x; ++b) r += sh[b * N_EXP + e];
      pb[e] = r;
      run += tot[e];
    }
    if (blockIdx.x == 0) offsets[N_EXP] = run;  // == 16384
  }
  __syncthreads();
  const int t = blockIdx.x * 256 + tid;
#pragma unroll
  for (int k = 0; k < 2; ++k) {
    int e = topk_idx[2 * t + k];
    int local = atomicAdd(&cur[e], 1);
    int pos = pb[e] + local;
    assign_token[pos] = t;
    assign_gate[pos] = topk_w[2 * t + k];
    slot_of[2 * t + k] = pos;  // inverse map for combine
  }
}

// ---------------- fp32 [E][R][C] -> bf16 [E][C][R] (transpose + convert) -----
__global__ __launch_bounds__(256) void transpose_cvt(
    const float* __restrict__ in, u16* __restrict__ out, int R, int C) {
  __shared__ u16 lds[64 * 66];
  const int e = blockIdx.z;
  const float* ip = in + (size_t)e * R * C;
  u16* op = out + (size_t)e * R * C;
  const int c0 = blockIdx.x * 64, r0 = blockIdx.y * 64;
  const int tid = threadIdx.x;
  const int tx = tid & 15, ty = tid >> 4;
#pragma unroll
  for (int i = 0; i < 4; ++i) {
    const int r = ty + i * 16;
    float4 v = *(const float4*)(ip + (size_t)(r0 + r) * C + c0 + tx * 4);
    ushort2 u01, u23;
    u01.x = f2bf(v.x); u01.y = f2bf(v.y);
    u23.x = f2bf(v.z); u23.y = f2bf(v.w);
    *(ushort2*)&lds[r * 66 + tx * 4] = u01;
    *(ushort2*)&lds[r * 66 + tx * 4 + 2] = u23;
  }
  __syncthreads();
  const int lane = tid & 63, wid = tid >> 6;
  const int r8 = lane & 7;
#pragma unroll
  for (int s = 0; s < 2; ++s) {
    const int c = s * 32 + wid * 8 + (lane >> 3);
    union { u16 u[8]; uint4 q; } pk;
#pragma unroll
    for (int k = 0; k < 8; ++k) pk.u[k] = lds[(r8 * 8 + k) * 66 + c];
    *(uint4*)(op + (size_t)(c0 + c) * R + r0 + r8 * 8) = pk.q;
  }
}

// ---------------- grouped GEMM: C[M][N] = A[M][K] * B[N][K]^T ---------------
// Round-4 proven structure (128x128 tile, BK=32, 4 waves) + T4 graft:
// DOUBLE-buffered LDS (32 KB) with COUNTED vmcnt(4) + raw s_barrier.
// Per iter: stage(buf^1, kt+1) [4 loads/thread issued] -> s_waitcnt vmcnt(4)
// [waits ONLY tile kt's 4 loads; next tile's stay in flight across both
// barriers] -> s_barrier -> compute(buf) -> s_barrier.  The vmcnt never
// drains to 0 in the loop, so the L2/HBM round-trip (~200-900 cy) that the
// old __syncthreads() drain exposed per K-step now hides under a full
// iteration of compute+sync.  Choreography race-verified in round 3
// (same counted-vmcnt + raw-barrier pattern, bit-exact result).
// XCD-aware remap (T1): expert e -> XCD e, mb fastest -> B panels L2-local
// (r4 measured FETCH 614->146 MB).
// FIRST:  A=xb(indirect via atok), B=w1b, epilogue = tanh-gelu -> bf16 -> h
// !FIRST: A=h (direct),            B=w2b, epilogue = *gate, fp32 -> y_slot
template <int LDA, int LDB, int LDC, int KITERS, int NXB, bool FIRST>
__global__ __launch_bounds__(256) void moe_gemm(
    const u16* __restrict__ Abase, const u16* __restrict__ Bbase,
    u16* __restrict__ hout, float* __restrict__ yout,
    const int* __restrict__ offsets, const float* __restrict__ assign_gate,
    const int* __restrict__ atok) {
  __shared__ __align__(16) u16 As[2 * 128 * 32];  // 16 KB (2 bufs)
  __shared__ __align__(16) u16 Bs[2 * 128 * 32];  // 16 KB (2 bufs)
  // ---- XCD-aware remap: xcd = flat%8 owns expert xcd; mb varies fastest ----
  const int flat = blockIdx.x + NXB * (blockIdx.y + MAX_MB * blockIdx.z);
  const int e = flat & 7;
  const int s = flat >> 3;           // 0 .. NXB*MAX_MB-1
  const int mb = s % MAX_MB;
  const int n0b = s / MAX_MB;        // 0 .. NXB-1
  const int row0 = offsets[e];
  const int cnt = offsets[e + 1] - row0;
  const int mbase = mb * 128;
  if (mbase >= cnt) return;  // block-uniform early exit
  const int mrem = cnt - mbase;
  const int n0 = n0b * 128;
  const int tid = threadIdx.x;
  const int lane = tid & 63;
  const int wid = tid >> 6;
  const int wm = wid & 1, wn = wid >> 1;
  const u16* B = Bbase + (size_t)e * ((size_t)H_DIM * F_DIM);
  const int row16 = lane & 15, quad = lane >> 4;
  const int srow = lane >> 2;        // staging: row within 16-row chunk
  const int scol = (lane & 3) * 8;   // staging: k-col (elements)

  // hoist per-thread A/B row pointers out of the K-loop (FIRST folds the
  // assign_token indirection here, once).
  const u16* Arow[2];
  const u16* Brow[2];
#pragma unroll
  for (int i = 0; i < 2; ++i) {
    const int c = wid * 2 + i;           // chunk 0..7 (16 rows x 64B each)
    const int r = c * 16 + srow;
    const int ra = min(r, mrem - 1);     // clamp: stay inside valid A rows
    if (FIRST) {
      const int tok = atok[row0 + mbase + ra];
      Arow[i] = Abase + (size_t)tok * LDA + scol;
    } else {
      Arow[i] = Abase + (size_t)(row0 + mbase + ra) * LDA + scol;
    }
    Brow[i] = B + (size_t)(n0 + r) * LDB + scol;
  }

  f32x4 acc[4][4];
#pragma unroll
  for (int i = 0; i < 4; ++i)
#pragma unroll
    for (int j = 0; j < 4; ++j)
#pragma unroll
      for (int r = 0; r < 4; ++r) acc[i][j][r] = 0.f;

  // stage one 128x32 K-tile pair into buffer `buf` (4 load16/thread)
  auto stage = [&](int buf, int kt) {
    const int k0 = kt * 32;
#pragma unroll
    for (int i = 0; i < 2; ++i) {
      const int c = wid * 2 + i;
      load16(Arow[i] + k0, &As[buf * 4096 + c * 512]);
      load16(Brow[i] + k0, &Bs[buf * 4096 + c * 512]);
    }
  };

  stage(0, 0);  // prologue: 4 loads/thread in flight
  int buf = 0;
#pragma unroll 1
  for (int kt = 0; kt < KITERS; ++kt) {
    const int ktn = (kt + 1 < KITERS) ? kt + 1 : kt;  // tail: harmless re-stage
    stage(buf ^ 1, ktn);  // now 8 loads/thread outstanding
    // wait until only the newest 4 (tile kt+1) remain -> tile kt landed
    asm volatile("s_waitcnt vmcnt(4)" ::: "memory");
    __builtin_amdgcn_sched_barrier(0);
    __builtin_amdgcn_s_barrier();  // all waves: tile kt fully in LDS
    __builtin_amdgcn_sched_barrier(0);
    {
      const u16* Ab = As + buf * 4096;
      const u16* Bb = Bs + buf * 4096;
      bf16x8 av[4], bv[4];
#pragma unroll
      for (int mi = 0; mi < 4; ++mi)
        av[mi] = *(const bf16x8*)&Ab[(wm * 64 + mi * 16 + row16) * 32 + quad * 8];
#pragma unroll
      for (int ni = 0; ni < 4; ++ni)
        bv[ni] = *(const bf16x8*)&Bb[(wn * 64 + ni * 16 + row16) * 32 + quad * 8];
#pragma unroll
      for (int mi = 0; mi < 4; ++mi)
#pragma unroll
        for (int ni = 0; ni < 4; ++ni)
          acc[mi][ni] =
              __builtin_amdgcn_mfma_f32_16x16x32_bf16(av[mi], bv[ni], acc[mi][ni], 0, 0, 0);
    }
    __builtin_amdgcn_sched_barrier(0);
    __builtin_amdgcn_s_barrier();  // all reads of buf done (next iter overwrites)
    __builtin_amdgcn_sched_barrier(0);
    buf ^= 1;
  }
  // drain the tail re-stage DMA before the workgroup can exit
  asm volatile("s_waitcnt vmcnt(0)" ::: "memory");

  // C/D layout: col = lane&15 (n), row = quad*4 + reg (m)
  if (FIRST) {
    u16* Cp = hout + (size_t)(row0 + mbase) * LDC + n0;
#pragma unroll
    for (int mi = 0; mi < 4; ++mi) {
#pragma unroll
      for (int r = 0; r < 4; ++r) {
        const int lm = wm * 64 + mi * 16 + quad * 4 + r;
        if (lm < mrem) {
#pragma unroll
          for (int ni = 0; ni < 4; ++ni) {
            float v = acc[mi][ni][r];
            // tanh-approx gelu via sigmoid: v * sigmoid(2*sqrt(2/pi)*(v+0.044715v^3))
            float t = v * (0.7978845608028654f + 0.0356774081363f * v * v);
            v = v / (1.f + __expf(-2.f * t));
            Cp[(size_t)lm * LDC + (wn * 64 + ni * 16 + row16)] = f2bf(v);
          }
        }
      }
    }
  } else {
#pragma unroll
    for (int mi = 0; mi < 4; ++mi) {
#pragma unroll
      for (int r = 0; r < 4; ++r) {
        const int lm = wm * 64 + mi * 16 + quad * 4 + r;
        if (lm < mrem) {
          const int slot = row0 + mbase + lm;
          const float g = assign_gate[slot];
          float* orow = yout + (size_t)slot * LDC + n0;
#pragma unroll
          for (int ni = 0; ni < 4; ++ni)
            orow[wn * 64 + ni * 16 + row16] = acc[mi][ni][r] * g;
        }
      }
    }
  }
}

// ---------------- combine: out[t] = y_slot[s0] + y_slot[s1] ------------------
__global__ __launch_bounds__(256) void combine_kernel(
    const float* __restrict__ ys, const int* __restrict__ slot_of,
    float* __restrict__ out) {
  const int t = blockIdx.x;
  const int s0 = slot_of[2 * t], s1 = slot_of[2 * t + 1];
  const int i = threadIdx.x;
  float4 a = ((const float4*)(ys + (size_t)s0 * H_DIM))[i];
  float4 b = ((const float4*)(ys + (size_t)s1 * H_DIM))[i];
  float4 o;
  o.x = a.x + b.x; o.y = a.y + b.y; o.z = a.z + b.z; o.w = a.w + b.w;
  ((float4*)(out + (size_t)t * H_DIM))[i] = o;
}

extern "C" void kernel_launch(void* const* d_in, const int* in_sizes, int n_in,
                              void* d_out, int out_size, void* d_ws, size_t ws_size,
                              hipStream_t stream) {
  const float* x = (const float*)d_in[0];
  const float* rw = (const float*)d_in[1];
  const float* rb = (const float*)d_in[2];
  const float* w1 = (const float*)d_in[3];
  const float* w2 = (const float*)d_in[4];
  float* out = (float*)d_out;

  char* ws = (char*)d_ws;
  // workspace layout (~302.4 MB total)
  u16* w1b = (u16*)(ws);                        // [E][F][H] bf16   67,108,864 B
  float* y_slot = (float*)(ws);                 // [16384][H] fp32 -- ALIASES w1b
                                                // (w1b dead after GEMM1; GEMM2 writes here)
  u16* w2b = (u16*)(ws + 67108864);             // [E][H][F] bf16   67,108,864 B
  u16* xb = (u16*)(ws + 134217728);             // [8192][H] bf16   16,777,216 B
  u16* h = (u16*)(ws + 167772160);              // [16384][F] bf16 134,217,728 B
  // hist borrows the head of the h region (dead before GEMM1 writes h)
  int* hist_g = (int*)(ws + 167772160);         // [32][8] ints (1 KB)
  char* meta = ws + 301989888;
  int* offsets = (int*)(meta + 64);             // 9 ints
  int* topk_idx = (int*)(meta + 128);           // 16384 ints
  float* topk_w = (float*)(meta + 128 + 65536);
  int* assign_token = (int*)(meta + 128 + 131072);
  float* assign_gate = (float*)(meta + 128 + 196608);
  int* slot_of = (int*)(meta + 128 + 262144);

  router_kernel<<<N_TOK / 4, 256, 0, stream>>>(x, rw, rb, topk_idx, topk_w, xb);
  hist_kernel<<<NMB, 256, 0, stream>>>(topk_idx, hist_g);
  scatter_kernel<<<NMB, 256, 0, stream>>>(topk_idx, topk_w, hist_g, offsets,
                                          assign_token, assign_gate, slot_of);
  // w1 [E][1024][4096] -> w1b [E][4096][1024]
  transpose_cvt<<<dim3(F_DIM / 64, H_DIM / 64, N_EXP), 256, 0, stream>>>(w1, w1b, H_DIM, F_DIM);
  // w2 [E][4096][1024] -> w2b [E][1024][4096]
  transpose_cvt<<<dim3(H_DIM / 64, F_DIM / 64, N_EXP), 256, 0, stream>>>(w2, w2b, F_DIM, H_DIM);

  // GEMM1: [cnt_e][1024] (indirect rows of xb) @ [4096][1024]^T -> gelu -> h
  moe_gemm<H_DIM, H_DIM, F_DIM, H_DIM / 32, F_DIM / 128, true>
      <<<dim3(F_DIM / 128, MAX_MB, N_EXP), 256, 0, stream>>>(
          xb, w1b, h, nullptr, offsets, assign_gate, assign_token);
  // GEMM2: [cnt_e][4096] @ [1024][4096]^T -> *gate -> y_slot [16384][1024]
  moe_gemm<F_DIM, F_DIM, H_DIM, F_DIM / 32, H_DIM / 128, false>
      <<<dim3(H_DIM / 128, MAX_MB, N_EXP), 256, 0, stream>>>(
          h, w2b, nullptr, y_slot, offsets, assign_gate, nullptr);
  // out[t] = y_slot[slot0(t)] + y_slot[slot1(t)]
  combine_kernel<<<N_TOK, 256, 0, stream>>>(y_slot, slot_of, out);

  (void)in_sizes; (void)n_in; (void)ws_size;
}